// Round 1
// baseline (74.046 us; speedup 1.0000x reference)
//
#include <hip/hip_runtime.h>

// CenterLoss: loss = sum(clip(distmat * onehot_mask, 1e-12, 1e12)) / B
// Only distmat[b, labels[b]] survives the mask; the (B*C - B) zeros each
// clamp to 1e-12 -> closed-form constant. So: per-row squared distance
// between x[b] and centers[labels[b]], clamp, sum, add constant, / B.

#define BATCH 4096
#define DIM 512
#define NUM_CLASSES 10000
#define ROWS_PER_BLOCK 4            // 4 waves * 64 lanes = 256 threads
#define NUM_BLOCKS (BATCH / ROWS_PER_BLOCK)   // 1024

__global__ __launch_bounds__(256) void center_loss_partial(
    const float* __restrict__ x,
    const int* __restrict__ labels,
    const float* __restrict__ centers,
    float* __restrict__ partials)
{
    const int wave = threadIdx.x >> 6;   // 0..3
    const int lane = threadIdx.x & 63;   // 0..63
    const int row  = blockIdx.x * ROWS_PER_BLOCK + wave;

    const int lbl = labels[row];

    // 512 floats = 128 float4 per row; 64 lanes -> 2 float4 per lane.
    const float4* xp = (const float4*)(x + (size_t)row * DIM);
    const float4* cp = (const float4*)(centers + (size_t)lbl * DIM);

    float4 a0 = xp[lane];
    float4 a1 = xp[lane + 64];
    float4 b0 = cp[lane];
    float4 b1 = cp[lane + 64];

    float d, acc = 0.0f;
    d = a0.x - b0.x; acc += d * d;
    d = a0.y - b0.y; acc += d * d;
    d = a0.z - b0.z; acc += d * d;
    d = a0.w - b0.w; acc += d * d;
    d = a1.x - b1.x; acc += d * d;
    d = a1.y - b1.y; acc += d * d;
    d = a1.z - b1.z; acc += d * d;
    d = a1.w - b1.w; acc += d * d;

    // wave-64 shuffle reduction
    #pragma unroll
    for (int off = 32; off > 0; off >>= 1)
        acc += __shfl_down(acc, off, 64);

    __shared__ float s[ROWS_PER_BLOCK];
    if (lane == 0) {
        // clamp applies per matrix entry, i.e. per row distance
        s[wave] = fminf(fmaxf(acc, 1e-12f), 1e12f);
    }
    __syncthreads();
    if (threadIdx.x == 0) {
        partials[blockIdx.x] = s[0] + s[1] + s[2] + s[3];
    }
}

__global__ __launch_bounds__(256) void center_loss_final(
    const float* __restrict__ partials,
    float* __restrict__ out)
{
    const int wave = threadIdx.x >> 6;
    const int lane = threadIdx.x & 63;

    float acc = 0.0f;
    for (int i = threadIdx.x; i < NUM_BLOCKS; i += 256)
        acc += partials[i];

    #pragma unroll
    for (int off = 32; off > 0; off >>= 1)
        acc += __shfl_down(acc, off, 64);

    __shared__ float s[4];
    if (lane == 0) s[wave] = acc;
    __syncthreads();
    if (threadIdx.x == 0) {
        double total = (double)s[0] + (double)s[1] + (double)s[2] + (double)s[3];
        // (B*C - B) exactly-zero masked entries, each clamped up to 1e-12
        total += (double)BATCH * (double)(NUM_CLASSES - 1) * 1e-12;
        out[0] = (float)(total / (double)BATCH);
    }
}

extern "C" void kernel_launch(void* const* d_in, const int* in_sizes, int n_in,
                              void* d_out, int out_size, void* d_ws, size_t ws_size,
                              hipStream_t stream) {
    const float* x       = (const float*)d_in[0];   // (4096, 512) f32
    const int*   labels  = (const int*)d_in[1];     // (4096,) int
    const float* centers = (const float*)d_in[2];   // (10000, 512) f32
    float* out = (float*)d_out;                     // scalar loss
    float* partials = (float*)d_ws;                 // NUM_BLOCKS floats

    center_loss_partial<<<NUM_BLOCKS, 256, 0, stream>>>(x, labels, centers, partials);
    center_loss_final<<<1, 256, 0, stream>>>(partials, out);
}